// Round 7
// baseline (208.187 us; speedup 1.0000x reference)
//
#include <hip/hip_runtime.h>
#include <cstdint>

#define B_ 2
#define E_ 16
#define HW_ 46080
#define P_ 92160
#define N_ 12
#define NINST 24
#define NBINS 512          // err in [0,2] -> bin = min(511, err*256)
#define BINSCALE 256.0f
#define SCH 90             // k_stats: 1024-px chunks per instance
#define ECH 360            // k_err: 256-px chunks per batch
#define NHALF 6            // instances per k_err block
#define NERRBLK (B_*2*ECH) // 1440
#define HISTN (NINST*NBINS)// 12288 u64 (+ticket slot at [HISTN])

typedef unsigned long long u64;
typedef unsigned int u32;

// ---- Pass 1: per-instance masked sum/sumsq/count partials (non-atomic) ------
// 2160 blocks; also zeroes the global hist+ticket region (runs before k_err).
// XCD swizzle: the 12 instance-blocks sharing one emb chunk get ids = x + 8*s
// with consecutive s, so they land on the same XCD (dispatch % 8 heuristic).
__global__ __launch_bounds__(256) void k_stats(const float* __restrict__ mf1,
                                               const float* __restrict__ mf2,
                                               const int* __restrict__ gt,
                                               float* __restrict__ partials,
                                               u64* __restrict__ hist){
  int L = blockIdx.x;              // 0..2159
  if(L < 49){                      // zero hist + ticket (12296 u64)
    int idx = L*256 + threadIdx.x;
    if(idx < HISTN+8) hist[idx] = 0ull;
  }
  int x = L & 7, s = L >> 3;       // s: 0..269
  int g = s / N_;
  int pr, n;
  if(g < 22){ pr = g*8 + x; n = s - g*N_; }
  else { int i2 = (s - 264)*8 + x; int q = i2/N_; pr = 176 + q; n = i2 - q*N_; }
  int b = pr / SCH, ch = pr - (pr/SCH)*SCH;
  int bn = b*N_ + n;

  int pbase = ch*1024;             // 1024 | HW_ so t uniform
  int t = (pbase >= HW_);
  int r0 = pbase - t*HW_ + threadIdx.x*4;
  const float* ep = (t ? mf2 : mf1) + (size_t)b*E_*HW_;

  int4 g4 = *(const int4*)&gt[(size_t)bn*P_ + pbase + threadIdx.x*4];
  float m0=(float)g4.x, m1=(float)g4.y, m2=(float)g4.z, m3=(float)g4.w;
  float vals[33];
  vals[32] = m0+m1+m2+m3;
  #pragma unroll
  for(int e=0;e<E_;e++){
    float4 xe = *(const float4*)&ep[(size_t)e*HW_ + r0];
    float a0=m0*xe.x, a1=m1*xe.y, a2=m2*xe.z, a3=m3*xe.w;
    vals[e] = (a0+a1)+(a2+a3);
    float q = a0*xe.x; q=fmaf(a1,xe.y,q); q=fmaf(a2,xe.z,q); q=fmaf(a3,xe.w,q);
    vals[E_+e] = q;
  }
  __shared__ float red[33];
  if(threadIdx.x < 33) red[threadIdx.x] = 0.f;
  __syncthreads();
  int lane = threadIdx.x & 63;
  float mine = 0.f;
  #pragma unroll
  for(int v=0; v<33; v++){
    float tt = vals[v];
    #pragma unroll
    for(int o=1;o<64;o<<=1) tt += __shfl_xor(tt, o, 64);
    if(lane==v) mine = tt;
  }
  if(lane < 33) atomicAdd(&red[lane], mine);
  __syncthreads();
  if(threadIdx.x < 33)
    partials[((size_t)bn*33 + threadIdx.x)*SCH + ch] = red[threadIdx.x];
}

// ---- Pass 2: errors -> histogram -> (last block) lovasz loss ---------------
__global__ __launch_bounds__(256) void k_err(const float* __restrict__ mf1,
                                             const float* __restrict__ mf2,
                                             const int* __restrict__ gt,
                                             const float* __restrict__ partials,
                                             u64* __restrict__ hist,
                                             float* __restrict__ out){
  __shared__ float red[NHALF][33];
  __shared__ float2 cAB[NHALF][E_];
  __shared__ float cK[NHALF];
  __shared__ u32 hh[NHALF*NBINS];          // 12 KB
  __shared__ u32 amLast;
  __shared__ float rs[4];

  int bx = blockIdx.x;                     // 0..3
  int b = bx >> 1, half = bx & 1;
  int n0 = half*NHALF;
  int ch = blockIdx.y;                     // 0..359
  int tid = threadIdx.x, lane = tid & 63, wave = tid >> 6;

  // reduce partials -> per-instance raw sums (redundant per block; L2-cheap)
  if(tid < NHALF*33){
    int n = tid/33, j = tid - n*33;
    const float* pp = partials + ((size_t)(b*N_+n0+n)*33 + j)*SCH;
    float sacc = 0.f;
    for(int c2=0;c2<SCH;c2++) sacc += pp[c2];
    red[n][j] = sacc;
  }
  for(int i=tid;i<NHALF*NBINS;i+=256) hh[i]=0u;
  __syncthreads();
  if(tid < NHALF){
    float c = red[tid][32];
    float k = 0.f;
    #pragma unroll
    for(int e=0;e<E_;e++){
      float mu = red[tid][e] / c;
      float v  = (red[tid][16+e] - c*mu*mu) / (c - 1.f);
      cAB[tid][e] = make_float2(v, -2.f*mu*v);
      k = fmaf(mu*mu, v, k);
    }
    cK[tid] = k;
  }
  __syncthreads();

  int p = ch*256 + tid;                    // 256 | HW_ -> t uniform
  int t = (p >= HW_);
  int r = p - t*HW_;
  const float* ep = (t ? mf2 : mf1) + (size_t)b*E_*HW_;
  float xr[E_];
  #pragma unroll
  for(int e=0;e<E_;e++) xr[e] = ep[(size_t)e*HW_ + r];

  #pragma unroll
  for(int n=0;n<NHALF;n++){
    int bn = b*N_ + n0 + n;
    float d = cK[n];
    #pragma unroll
    for(int e=0;e<E_;e++){
      float2 ab = cAB[n][e];
      d = fmaf(xr[e], fmaf(xr[e], ab.x, ab.y), d);
    }
    float logits = 2.f*__expf(-0.5f*d) - 1.f;
    int   mi = gt[(size_t)bn*P_ + p];
    float ev = fmaxf(1.f - logits*(2.f*(float)mi - 1.f), 0.f);
    int bin = min(NBINS-1, (int)(ev * BINSCALE));

    u64 mball = __ballot(mi != 0);
    u64 active = __ballot(1);
    while(active){
      int leader = __ffsll((unsigned long long)active) - 1;
      int lbin = __shfl(bin, leader, 64);
      u64 match = __ballot(bin == lbin);
      if(lane == leader){
        u32 cm = (u32)__popcll(match), lm = (u32)__popcll(match & mball);
        atomicAdd(&hh[n*NBINS + lbin], (cm<<16) | lm);
      }
      active &= ~match;
    }
  }
  __syncthreads();
  for(int i=tid;i<NHALF*NBINS;i+=256){
    u32 v = hh[i];
    if(v){
      int n = i >> 9, bin = i & (NBINS-1);
      atomicAdd(&hist[(size_t)(b*N_+n0+n)*NBINS + bin],
                ((u64)(v>>16)<<32) | (u64)(v & 0xffffu));
    }
  }
  __threadfence();
  if(tid==0){
    u64 old = atomicAdd(&hist[HISTN], 1ull);
    amLast = (old == (u64)(NERRBLK-1));
  }
  __syncthreads();

  if(amLast){                              // block-uniform
    __threadfence();
    float acc = 0.f;
    #pragma unroll
    for(int it=0; it<6; ++it){
      int bn = wave*6 + it;
      u64 loc[8]; u64 s = 0;
      #pragma unroll
      for(int k=0;k<8;k++){
        int bin = NBINS-1 - (lane*8 + k);
        loc[k] = __hip_atomic_load(&hist[(size_t)bn*NBINS + bin],
                                   __ATOMIC_RELAXED, __HIP_MEMORY_SCOPE_AGENT);
        s += loc[k];
      }
      u64 sc = s;
      #pragma unroll
      for(int o=1;o<64;o<<=1){ u64 v = __shfl_up(sc, o, 64); if(lane>=o) sc += v; }
      u64 tot = __shfl(sc, 63, 64);
      float G = (float)(u32)(tot & 0xffffffffu);
      u64 run = sc - s;                    // exclusive prefix
      #pragma unroll
      for(int k=0;k<8;k++){
        u64 lv = loc[k];
        u32 cb = (u32)(lv>>32), lb2 = (u32)(lv & 0xffffffffu);
        if(cb){
          int bin = NBINS-1 - (lane*8 + k);
          float mid = ((float)bin + 0.5f) * (1.0f/BINSCALE);
          float i0 = (float)(u32)(run>>32);
          float c0 = (float)(u32)(run & 0xffffffffu);
          float c1 = c0 + (float)lb2;
          float jend   = 1.f - (G - c1)/(G + i0 + (float)cb - c1);
          float jstart = 1.f - (G - c0)/(G + i0 - c0);   // i0=c0=0 -> 0
          acc += mid * (jend - jstart);
        }
        run += lv;
      }
    }
    #pragma unroll
    for(int o=32;o>0;o>>=1) acc += __shfl_down(acc, o, 64);
    if(lane==0) rs[wave] = acc;
    __syncthreads();
    if(tid==0) out[0] = (rs[0]+rs[1]+rs[2]+rs[3]) * (1.0f/(float)NINST);
  }
}

extern "C" void kernel_launch(void* const* d_in, const int* in_sizes, int n_in,
                              void* d_out, int out_size, void* d_ws, size_t ws_size,
                              hipStream_t stream){
  const float* mf1 = (const float*)d_in[0];
  const float* mf2 = (const float*)d_in[1];
  const int*   gt  = (const int*)d_in[2];
  float* out = (float*)d_out;

  // ws: partials f32[24][33][90] = 285120 B (fully overwritten each launch),
  //     hist u64[12288+8] after it (zeroed by k_stats each launch).
  float* partials = (float*)d_ws;
  u64*   hist     = (u64*)((char*)d_ws + 285120);

  k_stats<<<dim3(NINST*SCH), 256, 0, stream>>>(mf1, mf2, gt, partials, hist);
  k_err<<<dim3(B_*2, ECH), 256, 0, stream>>>(mf1, mf2, gt, partials, hist, out);
}

// Round 8
// 164.894 us; speedup vs baseline: 1.2625x; 1.2625x over previous
//
#include <hip/hip_runtime.h>
#include <cstdint>

#define B_ 2
#define E_ 16
#define HW_ 46080
#define P_ 92160
#define N_ 12
#define NINST 24
#define NBINS 512          // err in [0,2] -> bin = min(511, err*256)
#define BINSCALE 256.0f
#define SCH 30             // k_stats: 3072-px chunks per instance
#define ECH 360            // k_err: 256-px chunks per batch
#define NERRBLK (B_*ECH)   // 720
#define HISTN (NINST*NBINS)// 12288 u64 (+ticket slot at [HISTN])

typedef unsigned long long u64;
typedef unsigned int u32;

// ---- Pass 1: per-instance masked sum/sumsq/count chunk-partials ------------
// 720 blocks = 24 instances x 30 chunks of 3072 px. Non-atomic partial store
// (fully overwritten -> no zeroing). First 49 blocks zero hist+ticket region.
__global__ __launch_bounds__(256) void k_stats(const float* __restrict__ mf1,
                                               const float* __restrict__ mf2,
                                               const int* __restrict__ gt,
                                               float* __restrict__ partials,
                                               u64* __restrict__ hist){
  int L = blockIdx.x;              // 0..719
  if(L < 49){                      // zero hist + ticket (12296 u64)
    int idx = L*256 + threadIdx.x;
    if(idx < HISTN+8) hist[idx] = 0ull;
  }
  int bn = L / SCH, ch = L - bn*SCH;
  int b  = bn / N_;
  int pbase = ch*3072;             // 15 chunks per frame -> never straddles HW_
  const float* e1 = mf1 + (size_t)b*E_*HW_;
  const float* e2 = mf2 + (size_t)b*E_*HW_;
  const int*   gp = gt + (size_t)bn*P_;

  float s[E_], q[E_]; float c = 0.f;
  #pragma unroll
  for(int e=0;e<E_;e++){ s[e]=0.f; q[e]=0.f; }

  #pragma unroll
  for(int g=0; g<3; ++g){
    int p = pbase + g*1024 + threadIdx.x*4;
    int t = (p >= HW_);
    int r = p - t*HW_;
    const float* ep = t ? e2 : e1;
    int4 m4 = *(const int4*)&gp[p];
    float m0 = (float)m4.x, m1 = (float)m4.y, m2 = (float)m4.z, m3 = (float)m4.w;
    c += m0+m1+m2+m3;
    #pragma unroll
    for(int e=0;e<E_;e++){
      float4 x = *(const float4*)&ep[(size_t)e*HW_ + r];
      float a0 = m0*x.x, a1 = m1*x.y, a2 = m2*x.z, a3 = m3*x.w;
      s[e] += (a0+a1)+(a2+a3);
      float qq = a0*x.x; qq=fmaf(a1,x.y,qq); qq=fmaf(a2,x.z,qq); qq=fmaf(a3,x.w,qq);
      q[e] += qq;
    }
  }
  __shared__ float red[33];
  if(threadIdx.x < 33) red[threadIdx.x] = 0.f;
  __syncthreads();
  int lane = threadIdx.x & 63;
  float vals[33];
  #pragma unroll
  for(int e=0;e<E_;e++){ vals[e]=s[e]; vals[E_+e]=q[e]; }
  vals[32]=c;
  float mine = 0.f;
  #pragma unroll
  for(int v=0; v<33; v++){
    float tt = vals[v];
    #pragma unroll
    for(int o=1;o<64;o<<=1) tt += __shfl_xor(tt, o, 64);
    if(lane==v) mine = tt;
  }
  if(lane < 33) atomicAdd(&red[lane], mine);
  __syncthreads();
  if(threadIdx.x < 33)
    partials[((size_t)bn*33 + threadIdx.x)*SCH + ch] = red[threadIdx.x];
}

// ---- Pass 2: vA/vB/vK prologue + errors -> LDS hist -> (last block) loss ----
__global__ __launch_bounds__(256) void k_err(const float* __restrict__ mf1,
                                             const float* __restrict__ mf2,
                                             const int* __restrict__ gt,
                                             const float* __restrict__ partials,
                                             u64* __restrict__ hist,
                                             float* __restrict__ out){
  __shared__ float red[N_*33];
  __shared__ float cA[N_*E_], cB[N_*E_], cK[N_];
  __shared__ u32 hh[N_*NBINS];             // 24 KB
  __shared__ u32 amLast;
  __shared__ float rs[4];

  int b = blockIdx.x;                      // 0..1
  int ch = blockIdx.y;                     // 0..359
  int tid = threadIdx.x, lane = tid & 63, wave = tid >> 6;

  for(int i=tid;i<N_*NBINS;i+=256) hh[i]=0u;

  // reduce chunk-partials -> raw sums (396 (n,j) pairs, 30 elems each)
  for(int i=tid; i<N_*33; i+=256){
    int n = i/33, j = i - n*33;
    const float* pp = partials + ((size_t)(b*N_+n)*33 + j)*SCH;
    float sacc = 0.f;
    #pragma unroll
    for(int c2=0;c2<SCH;c2++) sacc += pp[c2];
    red[i] = sacc;
  }
  __syncthreads();
  if(tid < N_){
    float c = red[tid*33+32];
    float k = 0.f;
    #pragma unroll
    for(int e=0;e<E_;e++){
      float mu = red[tid*33+e] / c;
      float v  = (red[tid*33+16+e] - c*mu*mu) / (c - 1.f);
      cA[tid*E_+e] = v;
      cB[tid*E_+e] = -2.f*mu*v;
      k = fmaf(mu*mu, v, k);
    }
    cK[tid] = k;
  }
  __syncthreads();

  int p = ch*256 + tid;                    // 256 | HW_ -> t uniform per block
  int t = (p >= HW_);
  int r = p - t*HW_;
  const float* ep = (t ? mf2 : mf1) + (size_t)b*E_*HW_;
  float xr[E_];
  #pragma unroll
  for(int e=0;e<E_;e++) xr[e] = ep[(size_t)e*HW_ + r];

  #pragma unroll
  for(int n=0;n<N_;n++){
    int bn = b*N_ + n;
    float d = cK[n];
    #pragma unroll
    for(int e=0;e<E_;e++)
      d = fmaf(xr[e], fmaf(xr[e], cA[n*E_+e], cB[n*E_+e]), d);
    float logits = 2.f*__expf(-0.5f*d) - 1.f;
    int   mi = gt[(size_t)bn*P_ + p];
    float ev = fmaxf(1.f - logits*(2.f*(float)mi - 1.f), 0.f);
    int bin = min(NBINS-1, (int)(ev * BINSCALE));

    u64 mball = __ballot(mi != 0);
    u64 active = __ballot(1);
    while(active){
      int leader = __ffsll((unsigned long long)active) - 1;
      int lbin = __shfl(bin, leader, 64);
      u64 match = __ballot(bin == lbin);
      if(lane == leader){
        u32 cm = (u32)__popcll(match), lm = (u32)__popcll(match & mball);
        atomicAdd(&hh[n*NBINS + lbin], (cm<<16) | lm);
      }
      active &= ~match;
    }
  }
  __syncthreads();
  for(int i=tid;i<N_*NBINS;i+=256){
    u32 v = hh[i];
    if(v){
      int n = i >> 9, bin = i & (NBINS-1);
      atomicAdd(&hist[(size_t)(b*N_+n)*NBINS + bin],
                ((u64)(v>>16)<<32) | (u64)(v & 0xffffu));
    }
  }
  __threadfence();
  if(tid==0){
    u64 old = atomicAdd(&hist[HISTN], 1ull);
    amLast = (old == (u64)(NERRBLK-1));
  }
  __syncthreads();

  if(amLast){                              // block-uniform: the last block
    __threadfence();
    float acc = 0.f;
    #pragma unroll
    for(int it=0; it<6; ++it){
      int bn = wave*6 + it;
      u64 loc[8]; u64 s = 0;
      #pragma unroll
      for(int k=0;k<8;k++){
        int bin = NBINS-1 - (lane*8 + k);
        loc[k] = __hip_atomic_load(&hist[(size_t)bn*NBINS + bin],
                                   __ATOMIC_RELAXED, __HIP_MEMORY_SCOPE_AGENT);
        s += loc[k];
      }
      u64 sc = s;
      #pragma unroll
      for(int o=1;o<64;o<<=1){ u64 v = __shfl_up(sc, o, 64); if(lane>=o) sc += v; }
      u64 tot = __shfl(sc, 63, 64);
      float G = (float)(u32)(tot & 0xffffffffu);
      u64 run = sc - s;                    // exclusive prefix (descending order)
      #pragma unroll
      for(int k=0;k<8;k++){
        u64 lv = loc[k];
        u32 cb = (u32)(lv>>32), lb2 = (u32)(lv & 0xffffffffu);
        if(cb){
          int bin = NBINS-1 - (lane*8 + k);
          float mid = ((float)bin + 0.5f) * (1.0f/BINSCALE);
          float i0 = (float)(u32)(run>>32);
          float c0 = (float)(u32)(run & 0xffffffffu);
          float c1 = c0 + (float)lb2;
          float jend   = 1.f - (G - c1)/(G + i0 + (float)cb - c1);
          float jstart = 1.f - (G - c0)/(G + i0 - c0);   // i0=c0=0 -> 0
          acc += mid * (jend - jstart);
        }
        run += lv;
      }
    }
    #pragma unroll
    for(int o=32;o>0;o>>=1) acc += __shfl_down(acc, o, 64);
    if(lane==0) rs[wave] = acc;
    __syncthreads();
    if(tid==0) out[0] = (rs[0]+rs[1]+rs[2]+rs[3]) * (1.0f/(float)NINST);
  }
}

extern "C" void kernel_launch(void* const* d_in, const int* in_sizes, int n_in,
                              void* d_out, int out_size, void* d_ws, size_t ws_size,
                              hipStream_t stream){
  const float* mf1 = (const float*)d_in[0];
  const float* mf2 = (const float*)d_in[1];
  const int*   gt  = (const int*)d_in[2];
  float* out = (float*)d_out;

  // ws: partials f32[24][33][30] = 95040 B (fully overwritten each launch),
  //     hist u64[12288+8] after it (zeroed by k_stats's first blocks).
  float* partials = (float*)d_ws;
  u64*   hist     = (u64*)((char*)d_ws + 95040);

  k_stats<<<dim3(NINST*SCH), 256, 0, stream>>>(mf1, mf2, gt, partials, hist);
  k_err<<<dim3(B_, ECH), 256, 0, stream>>>(mf1, mf2, gt, partials, hist, out);
}